// Round 1
// baseline (1451.935 us; speedup 1.0000x reference)
//
#include <hip/hip_runtime.h>
#include <math.h>

// Problem: B=4, S=2048, D=1024, H=16, HD=64. Outputs: out (B,S,D) f32 then qk (B,H,S,S) f32.

typedef __bf16 bf16_t;
typedef __attribute__((ext_vector_type(8))) __bf16 bf16x8;
typedef __attribute__((ext_vector_type(4))) float floatx4;

#define GLOBAL_AS __attribute__((address_space(1)))
#define LDS_AS    __attribute__((address_space(3)))

__device__ __forceinline__ void load_lds16(const bf16_t* g, bf16_t* l) {
  // async global->LDS, 16B per lane; LDS dest = wave-uniform base + lane*16
  __builtin_amdgcn_global_load_lds((const GLOBAL_AS void*)g, (LDS_AS void*)l, 16, 0, 0);
}

// ---------------- cast f32 -> bf16 ----------------
__global__ __launch_bounds__(256) void cast_kernel(const float* __restrict__ in,
                                                   bf16_t* __restrict__ out, int n) {
  int i = blockIdx.x * 256 + threadIdx.x;
  if (i < n) out[i] = (bf16_t)in[i];
}

// ---------------- GEMM: C[M=8192,N=1024] = A[M,K=1024] @ W[N,K]^T ----------------
// MODE 0: dst bf16 in [b,h,s,hd] layout (+optional bias). MODE 1: dst f32 row-major (+bias).
template<int MODE>
__global__ __launch_bounds__(256) void gemm_bt(const bf16_t* __restrict__ A,
                                               const bf16_t* __restrict__ Bw,
                                               const float* __restrict__ bias,
                                               void* __restrict__ Cout) {
  __shared__ bf16_t As[128 * 32];
  __shared__ bf16_t Bs[128 * 32];
  const int tid = threadIdx.x;
  const int lane = tid & 63, quad = lane >> 4, c16 = lane & 15;
  const int wm = ((tid >> 7) & 1) * 64;  // wave row quadrant
  const int wn = ((tid >> 6) & 1) * 64;  // wave col quadrant
  const int m0 = blockIdx.y * 128, n0 = blockIdx.x * 128;
  const int wbase = tid & ~63;
  floatx4 acc[4][4] = {};

  for (int k0 = 0; k0 < 1024; k0 += 32) {
    __syncthreads();
    {
      int c0 = tid, c1 = 256 + tid;
      load_lds16(A  + (size_t)(m0 + (c0 >> 2)) * 1024 + k0 + (c0 & 3) * 8, As + (size_t)wbase * 8);
      load_lds16(A  + (size_t)(m0 + (c1 >> 2)) * 1024 + k0 + (c1 & 3) * 8, As + (size_t)(256 + wbase) * 8);
      load_lds16(Bw + (size_t)(n0 + (c0 >> 2)) * 1024 + k0 + (c0 & 3) * 8, Bs + (size_t)wbase * 8);
      load_lds16(Bw + (size_t)(n0 + (c1 >> 2)) * 1024 + k0 + (c1 & 3) * 8, Bs + (size_t)(256 + wbase) * 8);
    }
    __syncthreads();
    bf16x8 af[4], bfr[4];
#pragma unroll
    for (int i = 0; i < 4; ++i) af[i]  = *(const bf16x8*)&As[(wm + i * 16 + c16) * 32 + quad * 8];
#pragma unroll
    for (int j = 0; j < 4; ++j) bfr[j] = *(const bf16x8*)&Bs[(wn + j * 16 + c16) * 32 + quad * 8];
#pragma unroll
    for (int i = 0; i < 4; ++i)
#pragma unroll
      for (int j = 0; j < 4; ++j)
        acc[i][j] = __builtin_amdgcn_mfma_f32_16x16x32_bf16(af[i], bfr[j], acc[i][j], 0, 0, 0);
  }

#pragma unroll
  for (int i = 0; i < 4; ++i) {
#pragma unroll
    for (int j = 0; j < 4; ++j) {
#pragma unroll
      for (int r = 0; r < 4; ++r) {
        int row = m0 + wm + i * 16 + quad * 4 + r;   // C layout: row = quad*4+reg
        int col = n0 + wn + j * 16 + c16;            //           col = lane&15
        float v = acc[i][j][r];
        if (bias) v += bias[col];
        if (MODE == 0) {
          int b = row >> 11, s = row & 2047, h = col >> 6, hd = col & 63;
          ((bf16_t*)Cout)[(((size_t)(b * 16 + h) * 2048 + s) << 6) | hd] = (bf16_t)v;
        } else {
          ((float*)Cout)[(size_t)row * 1024 + col] = v;
        }
      }
    }
  }
}

// ---------------- RoPE + fold in HD^-0.25 scale, in place on q and k ----------------
__global__ __launch_bounds__(256) void rope_kernel(bf16_t* __restrict__ q, bf16_t* __restrict__ k,
                                                   const float* __restrict__ inv_freq,
                                                   const float* __restrict__ rbias) {
  int idx = blockIdx.x * 256 + threadIdx.x;  // 64 * 2048 * 32 pairs
  int f = idx & 31;
  int s = (idx >> 5) & 2047;
  int bh = idx >> 16;
  size_t base = (((size_t)bh * 2048 + s) << 6) + 2 * f;
  float fr = (float)s * inv_freq[f] + rbias[s * 32 + f];
  float sn, cs;
  sincosf(fr, &sn, &cs);
  const float SC = 0.35355339059327373f;  // 64^-0.25
  float cr = cs * SC, sr = sn * SC;
  float a = (float)q[base], b = (float)q[base + 1];
  q[base]     = (bf16_t)(a * cr - b * sr);
  q[base + 1] = (bf16_t)(a * sr + b * cr);
  a = (float)k[base]; b = (float)k[base + 1];
  k[base]     = (bf16_t)(a * cr - b * sr);
  k[base + 1] = (bf16_t)(a * sr + b * cr);
}

// ---------------- v [bh][s][hd] -> vt [bh][hd][s] ----------------
__global__ __launch_bounds__(256) void vtrans_kernel(const bf16_t* __restrict__ v,
                                                     bf16_t* __restrict__ vt) {
  __shared__ bf16_t tile[64][65];
  int bh = blockIdx.y, s0 = blockIdx.x * 64;
  const bf16_t* src = v + (((size_t)bh * 2048 + s0) << 6);
  int tid = threadIdx.x;
#pragma unroll
  for (int i = 0; i < 16; ++i) {
    int e = tid + i * 256;
    tile[e >> 6][e & 63] = src[e];
  }
  __syncthreads();
  bf16_t* dst = vt + ((size_t)bh << 17);
#pragma unroll
  for (int i = 0; i < 16; ++i) {
    int e = tid + i * 256;
    int hd = e >> 6, sc = e & 63;
    dst[(size_t)hd * 2048 + s0 + sc] = tile[sc][hd];
  }
}

// ---------------- fused attention ----------------
// grid (32 q-tiles, 64 bh); 4 waves, wave w owns q-rows [w*16, w*16+16).
// LDS rows are XOR-chunk-swizzled: element chunk cc (16B) of row r stored at cc^(r&mask).
__global__ __launch_bounds__(256) void attn_kernel(const bf16_t* __restrict__ qb,
                                                   const bf16_t* __restrict__ kb,
                                                   const bf16_t* __restrict__ vtb,
                                                   const float* __restrict__ mask,
                                                   float* __restrict__ qk_out,
                                                   bf16_t* __restrict__ attn_out) {
  __shared__ bf16_t Qs[64 * 64];    // [qrow][hd], swizzled (8 chunks/row)
  __shared__ bf16_t Ks[128 * 64];   // [kv][hd],   swizzled (8 chunks/row)
  __shared__ bf16_t Vs[64 * 128];   // [hd][kv],   swizzled (16 chunks/row)
  __shared__ bf16_t Ps[4][16 * 128];// per-wave P, swizzled (16 chunks/row)
  const int bh = blockIdx.y;
  const int q0 = blockIdx.x * 64;
  const int b = bh >> 4, h = bh & 15;
  const int tid = threadIdx.x, w = tid >> 6, lane = tid & 63;
  const int quad = lane >> 4, c16 = lane & 15;
  const int wbase = tid & ~63;

  // stage Q (swizzled source permutation)
  const bf16_t* qg = qb + (((size_t)bh * 2048 + q0) << 6);
  {
    int c0 = tid, c1 = 256 + tid;
    int r0 = c0 >> 3, cc0 = (c0 & 7) ^ (r0 & 7);
    int r1 = c1 >> 3, cc1 = (c1 & 7) ^ (r1 & 7);
    load_lds16(qg + (size_t)r0 * 64 + cc0 * 8, Qs + (size_t)wbase * 8);
    load_lds16(qg + (size_t)r1 * 64 + cc1 * 8, Qs + (size_t)(256 + wbase) * 8);
  }
  __syncthreads();
  bf16x8 qf[2];
  {
    int qr = w * 16 + c16;
    qf[0] = *(const bf16x8*)&Qs[qr * 64 + (((0 * 4 + quad) ^ (qr & 7)) * 8)];
    qf[1] = *(const bf16x8*)&Qs[qr * 64 + (((1 * 4 + quad) ^ (qr & 7)) * 8)];
  }

  float m_run[4] = {-1e30f, -1e30f, -1e30f, -1e30f};
  float l_run[4] = {0.f, 0.f, 0.f, 0.f};
  floatx4 o_acc[4] = {};
  const bf16_t* kg = kb  + ((size_t)bh << 17);
  const bf16_t* vg = vtb + ((size_t)bh << 17);
  const int qrl = w * 16 + quad * 4;  // local q-row base for C-layout rows

  for (int t = 0; t < 16; ++t) {
    const int k0 = t * 128;
    __syncthreads();
#pragma unroll
    for (int r = 0; r < 4; ++r) {   // K tile: 128x64 bf16
      int c = r * 256 + tid;
      int row = c >> 3, cc = (c & 7) ^ (row & 7);
      load_lds16(kg + (size_t)(k0 + row) * 64 + cc * 8, Ks + (size_t)(r * 256 + wbase) * 8);
    }
#pragma unroll
    for (int r = 0; r < 4; ++r) {   // V tile: 64x128 bf16 from [hd][s]
      int c = r * 256 + tid;
      int row = c >> 4, cc = (c & 15) ^ (row & 15);
      load_lds16(vg + (size_t)row * 2048 + k0 + cc * 8, Vs + (size_t)(r * 256 + wbase) * 8);
    }
    __syncthreads();

    // S = Q @ K^T  (per wave: 16 rows x 128 cols)
    floatx4 s_acc[8];
#pragma unroll
    for (int j = 0; j < 8; ++j) {
      floatx4 z = {0.f, 0.f, 0.f, 0.f};
      int kr = j * 16 + c16;
      bf16x8 kf0 = *(const bf16x8*)&Ks[kr * 64 + (((0 * 4 + quad) ^ (kr & 7)) * 8)];
      z = __builtin_amdgcn_mfma_f32_16x16x32_bf16(qf[0], kf0, z, 0, 0, 0);
      bf16x8 kf1 = *(const bf16x8*)&Ks[kr * 64 + (((1 * 4 + quad) ^ (kr & 7)) * 8)];
      s_acc[j] = __builtin_amdgcn_mfma_f32_16x16x32_bf16(qf[1], kf1, z, 0, 0, 0);
    }

    // mask add, qk store, row max
    float mloc[4] = {-1e30f, -1e30f, -1e30f, -1e30f};
    float* qkrow = qk_out + ((size_t)bh * 2048 + q0 + qrl) * 2048 + k0 + c16;
    const float* mrow = mask + (size_t)(q0 + qrl) * 2048 + k0 + c16;
#pragma unroll
    for (int j = 0; j < 8; ++j) {
#pragma unroll
      for (int r2 = 0; r2 < 4; ++r2) {
        float v = s_acc[j][r2] + mrow[(size_t)r2 * 2048 + j * 16];
        s_acc[j][r2] = v;
        qkrow[(size_t)r2 * 2048 + j * 16] = v;
        mloc[r2] = fmaxf(mloc[r2], v);
      }
    }
#pragma unroll
    for (int off = 8; off >= 1; off >>= 1)
#pragma unroll
      for (int r2 = 0; r2 < 4; ++r2)
        mloc[r2] = fmaxf(mloc[r2], __shfl_xor(mloc[r2], off));

    float alpha[4], lloc[4] = {0.f, 0.f, 0.f, 0.f};
#pragma unroll
    for (int r2 = 0; r2 < 4; ++r2) {
      float mn = fmaxf(m_run[r2], mloc[r2]);
      alpha[r2] = __expf(m_run[r2] - mn);
      m_run[r2] = mn;
    }
    // P = exp(S - m), write to LDS in swizzled layout
#pragma unroll
    for (int j = 0; j < 8; ++j)
#pragma unroll
      for (int r2 = 0; r2 < 4; ++r2) {
        float p = __expf(s_acc[j][r2] - m_run[r2]);
        lloc[r2] += p;
        int row = quad * 4 + r2, col = j * 16 + c16;
        Ps[w][row * 128 + (((col >> 3) ^ row) * 8) + (col & 7)] = (bf16_t)p;
      }
#pragma unroll
    for (int off = 8; off >= 1; off >>= 1)
#pragma unroll
      for (int r2 = 0; r2 < 4; ++r2)
        lloc[r2] += __shfl_xor(lloc[r2], off);
#pragma unroll
    for (int r2 = 0; r2 < 4; ++r2) {
      l_run[r2] = l_run[r2] * alpha[r2] + lloc[r2];
      o_acc[0][r2] *= alpha[r2];
      o_acc[1][r2] *= alpha[r2];
      o_acc[2][r2] *= alpha[r2];
      o_acc[3][r2] *= alpha[r2];
    }
    // O += P @ V
#pragma unroll
    for (int kc = 0; kc < 4; ++kc) {
      bf16x8 pf = *(const bf16x8*)&Ps[w][c16 * 128 + (((kc * 4 + quad) ^ c16) * 8)];
#pragma unroll
      for (int jo = 0; jo < 4; ++jo) {
        int vr = jo * 16 + c16;
        bf16x8 vf = *(const bf16x8*)&Vs[vr * 128 + (((kc * 4 + quad) ^ (vr & 15)) * 8)];
        o_acc[jo] = __builtin_amdgcn_mfma_f32_16x16x32_bf16(pf, vf, o_acc[jo], 0, 0, 0);
      }
    }
  }

  float inv[4];
#pragma unroll
  for (int r2 = 0; r2 < 4; ++r2) inv[r2] = 1.f / l_run[r2];
  bf16_t* arow = attn_out + ((size_t)(b * 2048 + q0 + qrl)) * 1024 + h * 64 + c16;
#pragma unroll
  for (int jo = 0; jo < 4; ++jo)
#pragma unroll
    for (int r2 = 0; r2 < 4; ++r2)
      arow[(size_t)r2 * 1024 + jo * 16] = (bf16_t)(o_acc[jo][r2] * inv[r2]);
}

extern "C" void kernel_launch(void* const* d_in, const int* in_sizes, int n_in,
                              void* d_out, int out_size, void* d_ws, size_t ws_size,
                              hipStream_t stream) {
  (void)in_sizes; (void)n_in; (void)out_size; (void)ws_size;
  const float* x        = (const float*)d_in[0];
  const float* Wq       = (const float*)d_in[1];
  const float* bq       = (const float*)d_in[2];
  const float* Wk       = (const float*)d_in[3];
  const float* Wv       = (const float*)d_in[4];
  const float* bv       = (const float*)d_in[5];
  const float* Wo       = (const float*)d_in[6];
  const float* bo       = (const float*)d_in[7];
  const float* inv_freq = (const float*)d_in[8];
  const float* rbias    = (const float*)d_in[9];
  const float* mask     = (const float*)d_in[10];

  bf16_t* xb   = (bf16_t*)d_ws;          // 8388608
  bf16_t* wqb  = xb   + 8388608;         // 1048576 each
  bf16_t* wkb  = wqb  + 1048576;
  bf16_t* wvb  = wkb  + 1048576;
  bf16_t* wob  = wvb  + 1048576;
  bf16_t* qbuf = wob  + 1048576;         // [bh][s][hd]
  bf16_t* kbuf = qbuf + 8388608;
  bf16_t* vbuf = kbuf + 8388608;
  bf16_t* vtb  = vbuf + 8388608;         // [bh][hd][s]
  bf16_t* attb = vtb  + 8388608;         // [b*s][d]

  float* out0 = (float*)d_out;
  float* qk   = out0 + (size_t)8388608;

  cast_kernel<<<32768, 256, 0, stream>>>(x,  xb,  8388608);
  cast_kernel<<<4096,  256, 0, stream>>>(Wq, wqb, 1048576);
  cast_kernel<<<4096,  256, 0, stream>>>(Wk, wkb, 1048576);
  cast_kernel<<<4096,  256, 0, stream>>>(Wv, wvb, 1048576);
  cast_kernel<<<4096,  256, 0, stream>>>(Wo, wob, 1048576);

  dim3 gg(8, 64);
  gemm_bt<0><<<gg, 256, 0, stream>>>(xb, wqb, bq, qbuf);
  gemm_bt<0><<<gg, 256, 0, stream>>>(xb, wkb, nullptr, kbuf);
  gemm_bt<0><<<gg, 256, 0, stream>>>(xb, wvb, bv, vbuf);

  rope_kernel<<<16384, 256, 0, stream>>>(qbuf, kbuf, inv_freq, rbias);
  vtrans_kernel<<<dim3(32, 64), 256, 0, stream>>>(vbuf, vtb);

  attn_kernel<<<dim3(32, 64), 256, 0, stream>>>(qbuf, kbuf, vtb, mask, qk, attb);

  gemm_bt<1><<<gg, 256, 0, stream>>>(attb, wob, bo, out0);
}